// Round 1
// baseline (30.631 us; speedup 1.0000x reference)
//
#include <hip/hip_runtime.h>

#define HH 2048
#define WW 2048
#define CC 3
#define OH 512
#define OW 512
#define TKR 8          // output rows per block
#define TKC 32         // output cols per block
#define ROWS 38        // 4*TKR + 6 halo
#define PITCH 136      // 4*TKC + 8 (start pad) ; multiple of 4 for float4
#define V4_PER_ROW 34  // PITCH/4

__global__ __launch_bounds__(256, 2)
void wpt2_kernel(const float* __restrict__ x,
                 const float* __restrict__ dec_lo,
                 const float* __restrict__ dec_hi,
                 float* __restrict__ out) {
    __shared__ float tile[ROWS * PITCH];

    const int tx  = threadIdx.x;              // 0..31 -> kc
    const int ty  = threadIdx.y;              // 0..7  -> kr
    const int tid = ty * TKC + tx;
    const int kc0 = blockIdx.x * TKC;
    const int kr0 = blockIdx.y * TKR;
    const int ch  = blockIdx.z;

    // ---------------- stage input tile to LDS ----------------
    // tile covers global rows [4*kr0-6, 4*kr0+31], cols [4*kc0-8, 4*kc0+127]
    const float* xc = x + (size_t)ch * HH * WW;
    const int r0 = 4 * kr0 - 6;
    const int c0 = 4 * kc0 - 8;
    for (int i = tid; i < ROWS * V4_PER_ROW; i += 256) {
        const int rr = i / V4_PER_ROW;
        const int vc = i - rr * V4_PER_ROW;
        int gr = r0 + rr;      if (gr < 0) gr += HH;   // whole-row wrap only
        int gc = c0 + 4 * vc;  if (gc < 0) gc += WW;   // whole-vec4 wrap only
        const float4 v = *reinterpret_cast<const float4*>(&xc[(size_t)gr * WW + gc]);
        *reinterpret_cast<float4*>(&tile[rr * PITCH + 4 * vc]) = v;
    }

    // ---------------- composed 10-tap filters (graycode band order) ----------------
    // GRAY[g] = (level1 band, level2 band): (0,0),(0,1),(1,1),(1,0)
    float lo[4], hi[4];
#pragma unroll
    for (int j = 0; j < 4; ++j) { lo[j] = dec_lo[j]; hi[j] = dec_hi[j]; }
    float F[4][10];
#pragma unroll
    for (int g = 0; g < 4; ++g) {
        const float* f1 = (g >= 2) ? hi : lo;             // level-1: 0,0,1,1
        const float* f2 = (g == 1 || g == 2) ? hi : lo;   // level-2: 0,1,1,0
#pragma unroll
        for (int d = 0; d < 10; ++d) F[g][d] = 0.f;
#pragma unroll
        for (int j2 = 0; j2 < 4; ++j2)
#pragma unroll
            for (int j1 = 0; j1 < 4; ++j1)
                F[g][2 * j2 + j1] = fmaf(f2[j2], f1[j1], F[g][2 * j2 + j1]);
    }

    __syncthreads();

    // ---------------- row pass: t[g][dc] over 10 taps dr ----------------
    // needed value for (dr,dc): x[4(kr0+ty)+3-dr][4(kc0+tx)+3-dc]
    //   -> tile[4*ty+9-dr][4*tx+11-dc]
    float t[4][10];
#pragma unroll
    for (int g = 0; g < 4; ++g)
#pragma unroll
        for (int d = 0; d < 10; ++d) t[g][d] = 0.f;

#pragma unroll
    for (int dr = 0; dr < 10; ++dr) {
        const int lr = 4 * ty + 9 - dr;
        const float* rp = &tile[lr * PITCH + 4 * tx];
        const float4 a = *reinterpret_cast<const float4*>(rp);
        const float4 b = *reinterpret_cast<const float4*>(rp + 4);
        const float4 c = *reinterpret_cast<const float4*>(rp + 8);
        const float row[12] = {a.x, a.y, a.z, a.w, b.x, b.y, b.z, b.w,
                               c.x, c.y, c.z, c.w};
#pragma unroll
        for (int dc = 0; dc < 10; ++dc) {
            const float v = row[11 - dc];
#pragma unroll
            for (int g = 0; g < 4; ++g)
                t[g][dc] = fmaf(F[g][dr], v, t[g][dc]);
        }
    }

    // ---------------- column combine + store 16 bands ----------------
    const int kr = kr0 + ty, kc = kc0 + tx;
#pragma unroll
    for (int gi = 0; gi < 4; ++gi) {
#pragma unroll
        for (int gj = 0; gj < 4; ++gj) {
            float acc = 0.f;
#pragma unroll
            for (int dc = 0; dc < 10; ++dc)
                acc = fmaf(F[gj][dc], t[gi][dc], acc);
            out[(((size_t)(ch * 16 + gi * 4 + gj)) * OH + kr) * OW + kc] = acc;
        }
    }
}

extern "C" void kernel_launch(void* const* d_in, const int* in_sizes, int n_in,
                              void* d_out, int out_size, void* d_ws, size_t ws_size,
                              hipStream_t stream) {
    const float* x      = (const float*)d_in[0];
    const float* dec_lo = (const float*)d_in[1];
    const float* dec_hi = (const float*)d_in[2];
    float* out          = (float*)d_out;

    dim3 grid(OW / TKC, OH / TKR, CC);   // 16 x 64 x 3
    dim3 block(TKC, TKR);                // 32 x 8 = 256
    hipLaunchKernelGGL(wpt2_kernel, grid, block, 0, stream, x, dec_lo, dec_hi, out);
}